// Round 5
// baseline (7339.590 us; speedup 1.0000x reference)
//
#include <hip/hip_runtime.h>

// Greedy NMS: keep[i] = !any(keep[j] for j in knn[i] if j < i)
//
// Round-5: single resident kernel, chained-chunk wavefront.
//   - 74 blocks x 512 threads, 2048 rows per chunk, all co-resident (74 <= 256 CUs).
//   - knn rows preloaded into registers in parallel across all blocks.
//   - progress counter (4 B in d_ws) advances chunk-by-chunk; block b resolves
//     external preds incrementally (GATE=1 passes over a 64-bit mask) while
//     waiting, runs the validated LDS monotone fixed-point for intra-chunk
//     deps on its turn, publishes flags to d_out, releases progress, then
//     writes its kept_knn rows off the critical path.
//
// Output encoding (validated round 4): INT32.
//   d_out[0..M)        : kept flags, 1 / 0          (ref output 0: bool)
//   d_out[M..M+M*64)   : kept_knn, idx or 150000    (ref output 1: int64)
//
// d_in[0]: nodes (float, unused)   d_in[1]: knn indices (int32, M*64)
// d_ws[0..3]: progress counter (zeroed by init kernel each call)

#define M_ROWS 150000
#define KNN    64
#define BLK    512
#define CHUNK  (BLK * 2)                          // 2048 rows per chunk
#define NCH    ((M_ROWS + CHUNK - 1) / CHUNK)     // 74 chunks
#define ICAP   6

__global__ void init_ws_kernel(unsigned int* progress) {
  if (threadIdx.x == 0) *progress = 0u;
}

__device__ __forceinline__ bool flag_kept(const int* out, int j) {
  int f = __hip_atomic_load(&out[j], __ATOMIC_RELAXED, __HIP_MEMORY_SCOPE_AGENT);
  return f != 0;
}

__global__ __launch_bounds__(BLK) void nms_chain_kernel(
    const int* __restrict__ knn,
    int* __restrict__ out,
    unsigned int* __restrict__ progress)
{
  const int b    = blockIdx.x;
  const int t    = threadIdx.x;
  const int base = b * CHUNK;
  const int rowA = base + 2 * t;
  const int rowB = rowA + 1;
  const bool vA  = rowA < M_ROWS;                 // M even: vA implies vB
  const bool vB  = rowB < M_ROWS;

  // ---- parallel phase: load both rows' indices into registers ----
  int v[2 * KNN];
  {
    if (vA) {
      const int4* rp = (const int4*)(knn + (long long)rowA * KNN);
#pragma unroll
      for (int q = 0; q < KNN / 4; ++q) {
        int4 d = rp[q];
        v[4*q+0] = d.x; v[4*q+1] = d.y; v[4*q+2] = d.z; v[4*q+3] = d.w;
      }
    } else {
#pragma unroll
      for (int k = 0; k < KNN; ++k) v[k] = M_ROWS;
    }
    if (vB) {
      const int4* rp2 = (const int4*)(knn + (long long)rowB * KNN);
#pragma unroll
      for (int q = 0; q < KNN / 4; ++q) {
        int4 d = rp2[q];
        v[KNN+4*q+0] = d.x; v[KNN+4*q+1] = d.y; v[KNN+4*q+2] = d.z; v[KNN+4*q+3] = d.w;
      }
    } else {
#pragma unroll
      for (int k = 0; k < KNN; ++k) v[KNN + k] = M_ROWS;
    }
  }

  __shared__ unsigned char  st[CHUNK];             // 0 unknown, 1 kept, 2 suppressed
  __shared__ unsigned short ilist[CHUNK][ICAP];    // intra-chunk pred offsets
  __shared__ unsigned int   prog_sh;

  // ---- classify preds: external (j < base, bitmask) vs internal list ----
  unsigned long long extA = 0ull, extB = 0ull;
  int icA = 0, icB = 0;
#pragma unroll
  for (int k = 0; k < KNN; ++k) {
    int j = v[k];
    if (vA && j < rowA) {                          // strict <: ref semantics
      if (j < base) extA |= (1ull << k);
      else { if (icA < ICAP) ilist[2*t][icA] = (unsigned short)(j - base); ++icA; }
    }
  }
#pragma unroll
  for (int k = 0; k < KNN; ++k) {
    int j = v[KNN + k];
    if (vB && j < rowB) {
      if (j < base) extB |= (1ull << k);
      else { if (icB < ICAP) ilist[2*t+1][icB] = (unsigned short)(j - base); ++icB; }
    }
  }
  const bool ovfA = icA > ICAP;                    // fallback: register rescan
  const bool ovfB = icB > ICAP;
  if (ovfA) icA = ICAP;
  if (ovfB) icB = ICAP;

  // ---- wait on progress; resolve external preds incrementally ----
  bool suppA = false, suppB = false;
  int p_done = 0;
  for (long long spin = 0; ; ++spin) {
    if (t == 0)
      prog_sh = __hip_atomic_load(progress, __ATOMIC_ACQUIRE, __HIP_MEMORY_SCOPE_AGENT);
    __syncthreads();
    const int praw = (int)prog_sh;
    const int p    = praw > b ? b : praw;          // defensive clamp
    const bool fin = (praw >= b);
    __syncthreads();                               // everyone read prog_sh
    if (fin || p > p_done) {
      const int lim = p * CHUNK;                   // rows < lim final in d_out
      if (extA) {
        if (suppA) extA = 0ull;
        else {
          bool s = false;
#pragma unroll
          for (int k = 0; k < KNN; ++k) {
            if ((extA >> k) & 1ull) {
              int j = v[k];
              if (j < lim) { extA &= ~(1ull << k); s |= flag_kept(out, j); }
            }
          }
          suppA |= s;
        }
      }
      if (extB) {
        if (suppB) extB = 0ull;
        else {
          bool s = false;
#pragma unroll
          for (int k = 0; k < KNN; ++k) {
            if ((extB >> k) & 1ull) {
              int j = v[KNN + k];
              if (j < lim) { extB &= ~(1ull << k); s |= flag_kept(out, j); }
            }
          }
          suppB |= s;
        }
      }
      p_done = p;
    }
    if (fin) break;
    if (spin > (1ll << 22)) break;                 // safety valve
    __builtin_amdgcn_s_sleep(1);
  }

  // ---- intra-chunk monotone fixed-point (validated round 4) ----
  st[2*t]   = (!vA || suppA) ? (unsigned char)2
            : ((icA == 0 && !ovfA) ? (unsigned char)1 : (unsigned char)0);
  st[2*t+1] = (!vB || suppB) ? (unsigned char)2
            : ((icB == 0 && !ovfB) ? (unsigned char)1 : (unsigned char)0);
  __syncthreads();

  for (int it = 0; it < CHUNK; ++it) {
    if (st[2*t] == 0) {
      bool anyK = false, allD = true;
      if (!ovfA) {
        for (int q = 0; q < icA; ++q) {
          unsigned char s = st[ilist[2*t][q]];
          anyK |= (s == 1); allD &= (s != 0);
        }
      } else {
#pragma unroll
        for (int k = 0; k < KNN; ++k) {
          int j = v[k];
          if (j >= base && j < rowA) {
            unsigned char s = st[j - base];
            anyK |= (s == 1); allD &= (s != 0);
          }
        }
      }
      if (anyK) st[2*t] = 2; else if (allD) st[2*t] = 1;
    }
    if (st[2*t+1] == 0) {
      bool anyK = false, allD = true;
      if (!ovfB) {
        for (int q = 0; q < icB; ++q) {
          unsigned char s = st[ilist[2*t+1][q]];
          anyK |= (s == 1); allD &= (s != 0);
        }
      } else {
#pragma unroll
        for (int k = 0; k < KNN; ++k) {
          int j = v[KNN + k];
          if (j >= base && j < rowB) {
            unsigned char s = st[j - base];
            anyK |= (s == 1); allD &= (s != 0);
          }
        }
      }
      if (anyK) st[2*t+1] = 2; else if (allD) st[2*t+1] = 1;
    }
    int nu = __syncthreads_count((int)((st[2*t] == 0) || (st[2*t+1] == 0)));
    if (nu == 0) break;
  }

  const bool kA = vA && (st[2*t] == 1);
  const bool kB = vB && (st[2*t+1] == 1);

  // ---- publish flags, then release progress ----
  if (vA) {
    int2 w; w.x = kA ? 1 : 0; w.y = kB ? 1 : 0;
    *((int2*)(out + rowA)) = w;                    // rowA even -> 8B aligned
  }
  __threadfence();
  __syncthreads();
  if (t == 0)
    __hip_atomic_store(progress, (unsigned int)(b + 1),
                       __ATOMIC_RELEASE, __HIP_MEMORY_SCOPE_AGENT);

  // ---- kept_knn writes (off the chain's critical path) ----
  if (vA) {
    int* orow = out + M_ROWS + (long long)rowA * KNN;
#pragma unroll
    for (int q = 0; q < 16; ++q) {
      int4 d;
      d.x = kA ? v[4*q+0] : M_ROWS;
      d.y = kA ? v[4*q+1] : M_ROWS;
      d.z = kA ? v[4*q+2] : M_ROWS;
      d.w = kA ? v[4*q+3] : M_ROWS;
      ((int4*)orow)[q] = d;
    }
  }
  if (vB) {
    int* orow = out + M_ROWS + (long long)rowB * KNN;
#pragma unroll
    for (int q = 0; q < 16; ++q) {
      int4 d;
      d.x = kB ? v[KNN+4*q+0] : M_ROWS;
      d.y = kB ? v[KNN+4*q+1] : M_ROWS;
      d.z = kB ? v[KNN+4*q+2] : M_ROWS;
      d.w = kB ? v[KNN+4*q+3] : M_ROWS;
      ((int4*)orow)[q] = d;
    }
  }
}

extern "C" void kernel_launch(void* const* d_in, const int* in_sizes, int n_in,
                              void* d_out, int out_size, void* d_ws, size_t ws_size,
                              hipStream_t stream) {
  const int* knn = (const int*)d_in[1];
  int* out = (int*)d_out;
  unsigned int* progress = (unsigned int*)d_ws;

  init_ws_kernel<<<1, 64, 0, stream>>>(progress);
  nms_chain_kernel<<<NCH, BLK, 0, stream>>>(knn, out, progress);
}

// Round 6
// 4356.078 us; speedup vs baseline: 1.6849x; 1.6849x over previous
//
#include <hip/hip_runtime.h>

// Greedy NMS: keep[i] = !any(keep[j] for j in knn[i] if j < i)
//
// Round-6: resident chained-chunk wavefront, ZERO per-thread arrays.
// Round-5 failed mode: int v[128] spilled to scratch (VGPR_Count=128) and the
// per-tick ext-resolve re-read 662 MB of spill lines on the critical path.
// Now: classification uses transient int4 loads; only 64-bit pending masks
// persist; resolve passes (GATE=16) reload pending knn words from L1/L2.
// kept_knn emission is a separate coalesced kernel so the chain kernel writes
// only 600 KB of flags (cheap __threadfence per block).
//
// Output encoding (validated round 4): INT32.
//   d_out[0..M)        : kept flags, 1 / 0
//   d_out[M..M+M*64)   : kept_knn, idx or 150000
// d_ws[0..3]: progress counter (zeroed by init kernel each call)

#define M_ROWS 150000
#define KNN    64
#define BLK    1024
#define CHUNK  2048                               // 2 rows/thread (block halves)
#define NCH    ((M_ROWS + CHUNK - 1) / CHUNK)     // 74 chunks
#define ICAP   6
#define GATE   16

__global__ void init_ws_kernel(unsigned int* progress) {
  if (threadIdx.x == 0) *progress = 0u;
}

__device__ __forceinline__ bool flag_kept(const int* out, int j) {
  return __hip_atomic_load(&out[j], __ATOMIC_RELAXED,
                           __HIP_MEMORY_SCOPE_AGENT) != 0;
}

__global__ __launch_bounds__(BLK) void nms_chain_kernel(
    const int* __restrict__ knn,
    int* __restrict__ out,
    unsigned int* __restrict__ progress)
{
  const int b    = blockIdx.x;
  const int t    = threadIdx.x;
  const int base = b * CHUNK;
  const int rowA = base + t;                      // first half of chunk
  const int rowB = base + BLK + t;                // second half of chunk
  const bool vA  = rowA < M_ROWS;
  const bool vB  = rowB < M_ROWS;
  const int* rA  = knn + (long long)rowA * KNN;
  const int* rB  = knn + (long long)rowB * KNN;

  __shared__ unsigned char  st[CHUNK];            // 0 unknown, 1 kept, 2 suppressed
  __shared__ unsigned short ilist[CHUNK][ICAP];   // intra-chunk pred offsets
  __shared__ unsigned int   prog_sh;

  // ---- classification (transient int4 loads; nothing kept but bitmasks) ----
  unsigned long long extA = 0ull, extB = 0ull;    // pending external preds
  int icA = 0, icB = 0;
  if (vA) {
#pragma unroll
    for (int q = 0; q < KNN / 4; ++q) {
      int4 d = ((const int4*)rA)[q];
      int js[4] = {d.x, d.y, d.z, d.w};
#pragma unroll
      for (int m = 0; m < 4; ++m) {
        int k = 4 * q + m, j = js[m];
        if (j < rowA) {                           // strict <: ref semantics
          if (j < base) extA |= (1ull << k);
          else { if (icA < ICAP) ilist[t][icA] = (unsigned short)(j - base); ++icA; }
        }
      }
    }
  }
  if (vB) {
#pragma unroll
    for (int q = 0; q < KNN / 4; ++q) {
      int4 d = ((const int4*)rB)[q];
      int js[4] = {d.x, d.y, d.z, d.w};
#pragma unroll
      for (int m = 0; m < 4; ++m) {
        int k = 4 * q + m, j = js[m];
        if (j < rowB) {
          if (j < base) extB |= (1ull << k);
          else { if (icB < ICAP) ilist[BLK + t][icB] = (unsigned short)(j - base); ++icB; }
        }
      }
    }
  }
  const bool ovfA = icA > ICAP;                   // fallback: global rescan
  const bool ovfB = icB > ICAP;
  if (ovfA) icA = ICAP;
  if (ovfB) icB = ICAP;

  // ---- wait on progress; gated incremental external resolution ----
  bool suppA = false, suppB = false;
  int p_done = 0;
  for (int spin = 0; ; ++spin) {
    if (t == 0)
      prog_sh = __hip_atomic_load(progress, __ATOMIC_ACQUIRE, __HIP_MEMORY_SCOPE_AGENT);
    __syncthreads();
    const int praw = (int)prog_sh;
    const bool fin = (praw >= b);
    const int p    = fin ? b : praw;
    __syncthreads();                              // all read prog_sh before rewrite
    if (fin || (p - p_done) >= GATE) {
      const int lim = p * CHUNK;                  // rows < lim are final in d_out
      if (suppA) extA = 0ull;
      if (extA) {
#pragma unroll
        for (int k = 0; k < KNN; ++k) {
          if ((extA >> k) & 1ull) {
            int j = rA[k];                        // L1/L2 reload, no scratch
            if (j < lim) { extA &= ~(1ull << k); if (flag_kept(out, j)) suppA = true; }
          }
        }
      }
      if (suppB) extB = 0ull;
      if (extB) {
#pragma unroll
        for (int k = 0; k < KNN; ++k) {
          if ((extB >> k) & 1ull) {
            int j = rB[k];
            if (j < lim) { extB &= ~(1ull << k); if (flag_kept(out, j)) suppB = true; }
          }
        }
      }
      p_done = p;
    }
    if (fin) break;
    if (spin > (1 << 22)) break;                  // safety valve
    __builtin_amdgcn_s_sleep(4);
  }

  // ---- intra-chunk monotone fixed-point (validated rounds 4/5) ----
  st[t]       = (!vA || suppA) ? (unsigned char)2
              : ((icA == 0 && !ovfA) ? (unsigned char)1 : (unsigned char)0);
  st[BLK + t] = (!vB || suppB) ? (unsigned char)2
              : ((icB == 0 && !ovfB) ? (unsigned char)1 : (unsigned char)0);
  __syncthreads();

  for (int it = 0; it < CHUNK; ++it) {
    if (st[t] == 0) {
      bool anyK = false, allD = true;
      if (!ovfA) {
        for (int q = 0; q < icA; ++q) {
          unsigned char s = st[ilist[t][q]];
          anyK |= (s == 1); allD &= (s != 0);
        }
      } else {
#pragma unroll
        for (int k = 0; k < KNN; ++k) {
          int j = rA[k];
          if (j >= base && j < rowA) {
            unsigned char s = st[j - base];
            anyK |= (s == 1); allD &= (s != 0);
          }
        }
      }
      if (anyK) st[t] = 2; else if (allD) st[t] = 1;
    }
    if (st[BLK + t] == 0) {
      bool anyK = false, allD = true;
      if (!ovfB) {
        for (int q = 0; q < icB; ++q) {
          unsigned char s = st[ilist[BLK + t][q]];
          anyK |= (s == 1); allD &= (s != 0);
        }
      } else {
#pragma unroll
        for (int k = 0; k < KNN; ++k) {
          int j = rB[k];
          if (j >= base && j < rowB) {
            unsigned char s = st[j - base];
            anyK |= (s == 1); allD &= (s != 0);
          }
        }
      }
      if (anyK) st[BLK + t] = 2; else if (allD) st[BLK + t] = 1;
    }
    int nu = __syncthreads_count((int)((st[t] == 0) || (st[BLK + t] == 0)));
    if (nu == 0) break;
  }

  // ---- publish flags only (600 KB total), then release progress ----
  if (vA) out[rowA] = (st[t] == 1) ? 1 : 0;
  if (vB) out[rowB] = (st[BLK + t] == 1) ? 1 : 0;
  __threadfence();
  __syncthreads();
  if (t == 0)
    __hip_atomic_store(progress, (unsigned int)(b + 1),
                       __ATOMIC_RELEASE, __HIP_MEMORY_SCOPE_AGENT);
}

// kept_knn writer: int4-vectorized, fully coalesced (validated round 4 scalar)
__global__ __launch_bounds__(256) void knn_out_kernel(
    const int* __restrict__ knn,
    int* __restrict__ out)
{
  const long long nq = (long long)M_ROWS * KNN / 4;     // int4 elements
  long long q = (long long)blockIdx.x * 256 + threadIdx.x;
  if (q >= nq) return;
  int row = (int)(q >> 4);                              // 16 int4 per row
  bool keep = out[row] != 0;                            // flags final
  int4 d = ((const int4*)knn)[q];
  int4 o;
  o.x = keep ? d.x : M_ROWS;
  o.y = keep ? d.y : M_ROWS;
  o.z = keep ? d.z : M_ROWS;
  o.w = keep ? d.w : M_ROWS;
  ((int4*)(out + M_ROWS))[q] = o;                       // 600000 B offset: 16B-aligned
}

extern "C" void kernel_launch(void* const* d_in, const int* in_sizes, int n_in,
                              void* d_out, int out_size, void* d_ws, size_t ws_size,
                              hipStream_t stream) {
  const int* knn = (const int*)d_in[1];
  int* out = (int*)d_out;
  unsigned int* progress = (unsigned int*)d_ws;

  init_ws_kernel<<<1, 64, 0, stream>>>(progress);
  nms_chain_kernel<<<NCH, BLK, 0, stream>>>(knn, out, progress);

  const long long nq = (long long)M_ROWS * KNN / 4;
  knn_out_kernel<<<(int)((nq + 255) / 256), 256, 0, stream>>>(knn, out);
}

// Round 7
// 978.952 us; speedup vs baseline: 7.4974x; 4.4497x over previous
//
#include <hip/hip_runtime.h>

// Greedy NMS: keep[i] = !any(keep[j] for j in knn[i] if j < i)
//
// Round-7: resident chained-chunk wavefront with an LDS keep-bitmask.
// Round-6 failure mode: per-bit conditional ext-resolve = ~128 DEPENDENT
// global-load latencies per pass (~57 us) on the critical path, plus
// acquire-per-poll buffer_inv storms. Now:
//   - keep bits published as a packed bitmask (32 x u64 ballots per chunk) via
//     relaxed AGENT (sc1/LLC-coherent) atomics into d_out's kept_knn region
//     (overwritten later by the writer kernel); d_ws = 4-byte progress only.
//   - polls are RELAXED (no cache invalidation).
//   - waiting blocks mirror published bits into LDS; pre-resolve passes
//     (GATE ticks + the b-1 tick) probe rows vs the LDS bitmask OFF-turn and
//     record the <=6 pending preds of the final 1-chunk window in LDS.
//   - on turn: copy 64 words, probe LDS pending lists, LDS fixed-point,
//     ballot-publish, release. ZERO bulk memory traffic at the chain head.
//
// Output encoding (validated round 4): INT32.
//   d_out[0..M)        : kept flags, 1 / 0
//   d_out[M..M+M*64)   : kept_knn, idx or 150000 (chain-time: bitmask scratch)
// d_ws[0..3]: progress counter (zeroed by init kernel each call)

#define M_ROWS 150000
#define KNN    64
#define BLK    1024
#define CHUNK  2048
#define NCH    ((M_ROWS + CHUNK - 1) / CHUNK)     // 74
#define ICAP   6
#define ECAP   6
#define GATE   16
#define LMW    4672                               // LDS bitmask words: 73*64

__global__ void init_ws_kernel(unsigned int* progress) {
  if (threadIdx.x == 0) *progress = 0u;
}

__device__ __forceinline__ unsigned int bm_load(const unsigned int* p) {
  return __hip_atomic_load(p, __ATOMIC_RELAXED, __HIP_MEMORY_SCOPE_AGENT);
}

// probe all preds j < lim of row rp against the LDS bitmask (rare/off-turn path)
__device__ __forceinline__ bool probe_row(const int* __restrict__ rp,
                                          const unsigned int* lm, int lim) {
  bool s = false;
#pragma unroll
  for (int q = 0; q < 16; ++q) {
    int4 d = ((const int4*)rp)[q];
    int js[4] = {d.x, d.y, d.z, d.w};
#pragma unroll
    for (int m = 0; m < 4; ++m) {
      int j = js[m];
      if (j < lim && ((lm[j >> 5] >> (j & 31)) & 1u)) s = true;
    }
  }
  return s;
}

__global__ __launch_bounds__(BLK) void nms_chain_kernel(
    const int* __restrict__ knn,
    int* __restrict__ out,
    unsigned int* __restrict__ progress)
{
  const int b    = blockIdx.x;
  const int t    = threadIdx.x;
  const int base = b * CHUNK;
  const int rowA = base + t;
  const int rowB = base + BLK + t;
  const bool vA  = rowA < M_ROWS;
  const bool vB  = rowB < M_ROWS;
  const int* rA  = knn + (long long)rowA * KNN;
  const int* rB  = knn + (long long)rowB * KNN;
  unsigned int* bmg = (unsigned int*)(out + M_ROWS);  // global bitmask u32[74*64]

  __shared__ unsigned int   lm[LMW];                  // mirrored keep bits
  __shared__ unsigned char  st[CHUNK];                // 0 unk, 1 kept, 2 supp
  __shared__ unsigned short il[CHUNK][ICAP];          // intra-chunk pred offsets
  __shared__ unsigned short exl[CHUNK][ECAP];         // final-window pred offsets
  __shared__ unsigned int   prog_sh;

  // ---- classification (parallel): build intra-chunk lists only ----
  int icA = 0, icB = 0;
  if (vA) {
#pragma unroll
    for (int q = 0; q < 16; ++q) {
      int4 d = ((const int4*)rA)[q];
      int js[4] = {d.x, d.y, d.z, d.w};
#pragma unroll
      for (int m = 0; m < 4; ++m) {
        int j = js[m];
        if (j >= base && j < rowA) {
          if (icA < ICAP) il[t][icA] = (unsigned short)(j - base);
          ++icA;
        }
      }
    }
  }
  if (vB) {
#pragma unroll
    for (int q = 0; q < 16; ++q) {
      int4 d = ((const int4*)rB)[q];
      int js[4] = {d.x, d.y, d.z, d.w};
#pragma unroll
      for (int m = 0; m < 4; ++m) {
        int j = js[m];
        if (j >= base && j < rowB) {
          if (icB < ICAP) il[BLK + t][icB] = (unsigned short)(j - base);
          ++icB;
        }
      }
    }
  }
  const bool ovfA = icA > ICAP;  if (ovfA) icA = ICAP;
  const bool ovfB = icB > ICAP;  if (ovfB) icB = ICAP;

  // ---- wait loop: mirror bits, pre-resolve off-turn, record final window ----
  bool suppA = false, suppB = false;
  bool haveList = false, exovfA = false, exovfB = false;
  int  ecA = 0, ecB = 0;
  int  p_done = 0, wcop = 0;
  const int limL = (b - 1) * CHUNK;                   // final-window base (b>=1)

  for (int spin = 0; ; ++spin) {
    if (t == 0)
      prog_sh = __hip_atomic_load(progress, __ATOMIC_RELAXED, __HIP_MEMORY_SCOPE_AGENT);
    __syncthreads();
    const int praw = (int)prog_sh;
    const bool fin = (praw >= b);
    const int p    = fin ? b : praw;
    const bool doPass = !fin && ((p - p_done >= GATE) || (p == b - 1 && !haveList));

    if (doPass || fin) {
      const int wt = p * 64;                          // bitmask words < p*CHUNK
      for (int w = wcop + t; w < wt; w += BLK)
        lm[w] = bm_load(&bmg[w]);
      wcop = wt;
      __syncthreads();                                // lm visible to all
      if (doPass) {
        const int lim = p * CHUNK;
        const bool rec = (p == b - 1);
        if (vA && !suppA) {
          bool s = false;
#pragma unroll
          for (int q = 0; q < 16; ++q) {
            int4 d = ((const int4*)rA)[q];
            int js[4] = {d.x, d.y, d.z, d.w};
#pragma unroll
            for (int m = 0; m < 4; ++m) {
              int j = js[m];
              if (j < lim) { if ((lm[j >> 5] >> (j & 31)) & 1u) s = true; }
              else if (rec && j < base) {
                if (ecA < ECAP) exl[t][ecA] = (unsigned short)(j - lim);
                ++ecA;
              }
            }
          }
          suppA |= s;
        }
        if (vB && !suppB) {
          bool s = false;
#pragma unroll
          for (int q = 0; q < 16; ++q) {
            int4 d = ((const int4*)rB)[q];
            int js[4] = {d.x, d.y, d.z, d.w};
#pragma unroll
            for (int m = 0; m < 4; ++m) {
              int j = js[m];
              if (j < lim) { if ((lm[j >> 5] >> (j & 31)) & 1u) s = true; }
              else if (rec && j < base) {
                if (ecB < ECAP) exl[BLK + t][ecB] = (unsigned short)(j - lim);
                ++ecB;
              }
            }
          }
          suppB |= s;
        }
        if (rec) {
          exovfA = ecA > ECAP;  if (exovfA) ecA = ECAP;
          exovfB = ecB > ECAP;  if (exovfB) ecB = ECAP;
          haveList = true;
        }
        p_done = p;
      }
    }
    __syncthreads();                                  // prog_sh reuse guard
    if (fin) break;
    if (spin > (1 << 22)) break;                      // safety valve
    __builtin_amdgcn_s_sleep(2);
  }

  // ---- final window resolution (LDS-only fast path) ----
  if (haveList) {                                     // pending covers [limL, base)
    if (vA && !suppA) {
      if (!exovfA) {
        for (int q = 0; q < ecA; ++q) {
          int j = limL + (int)exl[t][q];
          if ((lm[j >> 5] >> (j & 31)) & 1u) { suppA = true; break; }
        }
      } else suppA = probe_row(rA, lm, base);         // rare
    }
    if (vB && !suppB) {
      if (!exovfB) {
        for (int q = 0; q < ecB; ++q) {
          int j = limL + (int)exl[BLK + t][q];
          if ((lm[j >> 5] >> (j & 31)) & 1u) { suppB = true; break; }
        }
      } else suppB = probe_row(rB, lm, base);         // rare
    }
  } else if (b > 0) {                                 // missed b-1 tick (rare)
    if (vA && !suppA) suppA = probe_row(rA, lm, base);
    if (vB && !suppB) suppB = probe_row(rB, lm, base);
  }

  // ---- intra-chunk monotone fixed-point (validated rounds 4-6) ----
  st[t]       = (!vA || suppA) ? (unsigned char)2
              : ((icA == 0 && !ovfA) ? (unsigned char)1 : (unsigned char)0);
  st[BLK + t] = (!vB || suppB) ? (unsigned char)2
              : ((icB == 0 && !ovfB) ? (unsigned char)1 : (unsigned char)0);
  __syncthreads();

  for (int it = 0; it < CHUNK; ++it) {
    if (st[t] == 0) {
      bool anyK = false, allD = true;
      if (!ovfA) {
        for (int q = 0; q < icA; ++q) {
          unsigned char s = st[il[t][q]];
          anyK |= (s == 1); allD &= (s != 0);
        }
      } else {
#pragma unroll
        for (int k = 0; k < KNN; ++k) {
          int j = rA[k];
          if (j >= base && j < rowA) {
            unsigned char s = st[j - base];
            anyK |= (s == 1); allD &= (s != 0);
          }
        }
      }
      if (anyK) st[t] = 2; else if (allD) st[t] = 1;
    }
    if (st[BLK + t] == 0) {
      bool anyK = false, allD = true;
      if (!ovfB) {
        for (int q = 0; q < icB; ++q) {
          unsigned char s = st[il[BLK + t][q]];
          anyK |= (s == 1); allD &= (s != 0);
        }
      } else {
#pragma unroll
        for (int k = 0; k < KNN; ++k) {
          int j = rB[k];
          if (j >= base && j < rowB) {
            unsigned char s = st[j - base];
            anyK |= (s == 1); allD &= (s != 0);
          }
        }
      }
      if (anyK) st[BLK + t] = 2; else if (allD) st[BLK + t] = 1;
    }
    int nu = __syncthreads_count((int)((st[t] == 0) || (st[BLK + t] == 0)));
    if (nu == 0) break;
  }

  // ---- ballot-publish keep bits, then release progress ----
  const bool kA = vA && (st[t] == 1);
  const bool kB = vB && (st[BLK + t] == 1);
  unsigned long long baA = __ballot(kA);              // rows base + (t/64)*64 + lane
  unsigned long long baB = __ballot(kB);              // rows base + 1024 + ...
  if ((t & 63) == 0) {
    unsigned long long* bmg64 = (unsigned long long*)bmg;
    const int w = t >> 6;                             // 0..15
    __hip_atomic_store(&bmg64[b * 32 + w], baA,
                       __ATOMIC_RELAXED, __HIP_MEMORY_SCOPE_AGENT);
    __hip_atomic_store(&bmg64[b * 32 + 16 + w], baB,
                       __ATOMIC_RELAXED, __HIP_MEMORY_SCOPE_AGENT);
  }
  __syncthreads();                                    // drains stores (vmcnt 0)
  if (t == 0)
    __hip_atomic_store(progress, (unsigned int)(b + 1),
                       __ATOMIC_RELEASE, __HIP_MEMORY_SCOPE_AGENT);

  // ---- write int32 flags (off the chain) ----
  if (vA) out[rowA] = kA ? 1 : 0;
  if (vB) out[rowB] = kB ? 1 : 0;
}

// kept_knn writer: int4-vectorized, fully coalesced (validated round 6);
// overwrites the bitmask scratch region.
__global__ __launch_bounds__(256) void knn_out_kernel(
    const int* __restrict__ knn,
    int* __restrict__ out)
{
  const long long nq = (long long)M_ROWS * KNN / 4;
  long long q = (long long)blockIdx.x * 256 + threadIdx.x;
  if (q >= nq) return;
  int row = (int)(q >> 4);
  bool keep = out[row] != 0;
  int4 d = ((const int4*)knn)[q];
  int4 o;
  o.x = keep ? d.x : M_ROWS;
  o.y = keep ? d.y : M_ROWS;
  o.z = keep ? d.z : M_ROWS;
  o.w = keep ? d.w : M_ROWS;
  ((int4*)(out + M_ROWS))[q] = o;
}

extern "C" void kernel_launch(void* const* d_in, const int* in_sizes, int n_in,
                              void* d_out, int out_size, void* d_ws, size_t ws_size,
                              hipStream_t stream) {
  const int* knn = (const int*)d_in[1];
  int* out = (int*)d_out;
  unsigned int* progress = (unsigned int*)d_ws;

  init_ws_kernel<<<1, 64, 0, stream>>>(progress);
  nms_chain_kernel<<<NCH, BLK, 0, stream>>>(knn, out, progress);

  const long long nq = (long long)M_ROWS * KNN / 4;
  knn_out_kernel<<<(int)((nq + 255) / 256), 256, 0, stream>>>(knn, out);
}

// Round 8
// 951.594 us; speedup vs baseline: 7.7129x; 1.0287x over previous
//
#include <hip/hip_runtime.h>

// Greedy NMS: keep[i] = !any(keep[j] for j in knn[i] if j < i)
//
// Round-8: resident chained-chunk wavefront, 37 x 4096-row chunks.
//   - keep bits ballot-published as a packed bitmask into the LAST 72 rows'
//     kept_knn slots (end of d_out); block 36 skips publishing (no reader)
//     so its own kept_knn writes cannot race the bitmask. d_ws = 4 B progress.
//   - relaxed polls, ONE barrier per poll iteration (double-buffered slot).
//   - final-window (previous chunk) pred lists recorded at CLASSIFICATION
//     time (window is static) -> no row reload on the critical path.
//   - publish: ballots -> LDS -> wave 0 stores 64 words + release (wave-local
//     vmcnt ordering); only one full barrier in the publish path.
//   - kept_knn written by each block after its release (overlapped).
//
// Output encoding (validated round 4): INT32.
//   d_out[0..M)        : kept flags, 1 / 0
//   d_out[M..M+M*64)   : kept_knn, idx or 150000 (tail doubles as bitmask scratch)
// d_ws[0..3]: progress counter (zeroed by init kernel each call)

#define M_ROWS 150000
#define KNN    64
#define BLK    1024
#define QRT    4
#define CHUNK  (BLK * QRT)                        // 4096
#define NCH    ((M_ROWS + CHUNK - 1) / CHUNK)     // 37
#define ICAP   6
#define ECAP   8
#define GATE   12
#define LMW    (((NCH - 1) * CHUNK) / 32)         // 4608 u32 bitmask words
#define OUT_INTS (M_ROWS + M_ROWS * KNN)          // 9,750,000
#define BMG_OFF  (OUT_INTS - LMW)                 // scratch in last 72 rows' knn

__global__ void init_ws_kernel(unsigned int* progress) {
  if (threadIdx.x == 0) *progress = 0u;
}

__device__ __forceinline__ unsigned int bm_load(const unsigned int* p) {
  return __hip_atomic_load(p, __ATOMIC_RELAXED, __HIP_MEMORY_SCOPE_AGENT);
}

// reload a row and probe preds j in [lo, hi) against the LDS bitmask
__device__ __forceinline__ bool probe_reload(const int* __restrict__ rp,
                                             const unsigned int* lm,
                                             int lo, int hi) {
  bool s = false;
#pragma unroll
  for (int u = 0; u < 16; ++u) {
    int4 d = ((const int4*)rp)[u];
    int js[4] = {d.x, d.y, d.z, d.w};
#pragma unroll
    for (int m = 0; m < 4; ++m) {
      int j = js[m];
      if (j >= lo && j < hi && ((lm[j >> 5] >> (j & 31)) & 1u)) s = true;
    }
  }
  return s;
}

__global__ __launch_bounds__(BLK) void nms_chain_kernel(
    const int* __restrict__ knn,
    int* __restrict__ out,
    unsigned int* __restrict__ progress)
{
  const int b    = blockIdx.x;
  const int t    = threadIdx.x;
  const int base = b * CHUNK;
  const int winb = base - CHUNK;                  // final-window base (b>=1)

  unsigned int* bmg = (unsigned int*)out + BMG_OFF;
  unsigned long long* bmg64 = (unsigned long long*)bmg;

  __shared__ unsigned char      st[CHUNK];        // 0 unk, 1 kept, 2 supp
  __shared__ unsigned short     il[CHUNK][ICAP];  // intra-chunk pred offsets
  __shared__ unsigned short     exl[CHUNK][ECAP]; // final-window pred offsets
  __shared__ unsigned int       lm[LMW];          // mirrored keep bits
  __shared__ unsigned long long bw[QRT][BLK / 64];
  __shared__ unsigned int       prog_sh[2];

  int  rowq[QRT];
  bool vq[QRT], ovf[QRT], eovf[QRT], supp[QRT];
  int  ic[QRT], ec[QRT];

#pragma unroll
  for (int q = 0; q < QRT; ++q) {
    rowq[q] = base + q * BLK + t;
    vq[q]   = rowq[q] < M_ROWS;
    ic[q] = ec[q] = 0;
    ovf[q] = eovf[q] = supp[q] = false;
  }

  // ---- classification: intra-chunk + static final-window lists ----
#pragma unroll
  for (int q = 0; q < QRT; ++q) {
    if (!vq[q]) continue;
    const int o   = q * BLK + t;
    const int row = rowq[q];
    const int* rp = knn + (long long)row * KNN;
#pragma unroll
    for (int u = 0; u < 16; ++u) {
      int4 d = ((const int4*)rp)[u];
      int js[4] = {d.x, d.y, d.z, d.w};
#pragma unroll
      for (int m = 0; m < 4; ++m) {
        int j = js[m];
        if (j < row) {                            // strict <: ref semantics
          if (j >= base) {
            if (ic[q] < ICAP) il[o][ic[q]] = (unsigned short)(j - base);
            ++ic[q];
          } else if (j >= winb) {
            if (ec[q] < ECAP) exl[o][ec[q]] = (unsigned short)(j - winb);
            ++ec[q];
          }
          // j < winb: handled by gate passes / on-turn catch-up
        }
      }
    }
  }
#pragma unroll
  for (int q = 0; q < QRT; ++q) {
    ovf[q]  = ic[q] > ICAP; if (ovf[q])  ic[q] = ICAP;
    eovf[q] = ec[q] > ECAP; if (eovf[q]) ec[q] = ECAP;
  }

  // ---- wait loop: one barrier/iter; mirror bits; gated pre-resolve ----
  int p_done = 0, wcop = 0;
  for (int spin = 0; ; ++spin) {
    const int slot = spin & 1;
    if (t == 0)
      prog_sh[slot] = __hip_atomic_load(progress, __ATOMIC_RELAXED,
                                        __HIP_MEMORY_SCOPE_AGENT);
    __syncthreads();                              // slot reuse safe: 1 barrier apart
    const int praw = (int)prog_sh[slot];
    const bool fin = (praw >= b);
    const int  p   = fin ? b : praw;
    const bool pass = fin ? (wcop < b * (CHUNK / 32))
                          : ((p - p_done >= GATE) ||
                             (p == b - 1 && p_done < b - 1));
    if (pass) {
      const int wt = p * (CHUNK / 32);
      for (int w = wcop + t; w < wt; w += BLK) lm[w] = bm_load(&bmg[w]);
      wcop = wt;
      __syncthreads();                            // lm visible
      if (!fin) {
        const int lim = p * CHUNK;
#pragma unroll
        for (int q = 0; q < QRT; ++q) {
          if (vq[q] && !supp[q])
            supp[q] = probe_reload(knn + (long long)rowq[q] * KNN, lm, 0, lim);
        }
        p_done = p;
      }
    }
    if (fin) break;
    if (spin > (1 << 22)) break;                  // safety valve
    __builtin_amdgcn_s_sleep(1);
  }

  // ---- on-turn: leftover pre-window (rare) + final-window LDS probes ----
  if (b > 0) {
    if (p_done < b - 1) {                         // missed ticks (rare)
#pragma unroll
      for (int q = 0; q < QRT; ++q)
        if (vq[q] && !supp[q])
          supp[q] = probe_reload(knn + (long long)rowq[q] * KNN, lm, 0, winb);
    }
#pragma unroll
    for (int q = 0; q < QRT; ++q) {
      if (!vq[q] || supp[q]) continue;
      if (!eovf[q]) {
        const int o = q * BLK + t;
        for (int x = 0; x < ec[q]; ++x) {
          int j = winb + (int)exl[o][x];
          if ((lm[j >> 5] >> (j & 31)) & 1u) { supp[q] = true; break; }
        }
      } else {                                    // >ECAP window preds (rare)
        supp[q] = probe_reload(knn + (long long)rowq[q] * KNN, lm, winb, base);
      }
    }
  }

  // ---- intra-chunk monotone fixed-point (validated rounds 4-7) ----
#pragma unroll
  for (int q = 0; q < QRT; ++q) {
    const int o = q * BLK + t;
    st[o] = (!vq[q] || supp[q]) ? (unsigned char)2
          : ((ic[q] == 0 && !ovf[q]) ? (unsigned char)1 : (unsigned char)0);
  }
  __syncthreads();

  for (int it = 0; it < CHUNK; ++it) {
    bool un = false;
#pragma unroll
    for (int q = 0; q < QRT; ++q) {
      const int o = q * BLK + t;
      if (st[o] == 0) {
        bool anyK = false, allD = true;
        if (!ovf[q]) {
          for (int x = 0; x < ic[q]; ++x) {
            unsigned char s = st[il[o][x]];
            anyK |= (s == 1); allD &= (s != 0);
          }
        } else {                                  // rare: rescan from global
          const int row = rowq[q];
          const int* rp = knn + (long long)row * KNN;
#pragma unroll
          for (int k = 0; k < KNN; ++k) {
            int j = rp[k];
            if (j >= base && j < row) {
              unsigned char s = st[j - base];
              anyK |= (s == 1); allD &= (s != 0);
            }
          }
        }
        if (anyK) st[o] = 2; else if (allD) st[o] = 1;
        if (st[o] == 0) un = true;
      }
    }
    if (__syncthreads_count((int)un) == 0) break;
  }

  // ---- publish: ballots -> LDS -> wave 0 stores + release ----
  bool kq[QRT];
#pragma unroll
  for (int q = 0; q < QRT; ++q)
    kq[q] = vq[q] && (st[q * BLK + t] == 1);

#pragma unroll
  for (int q = 0; q < QRT; ++q) {
    unsigned long long ba = __ballot(kq[q]);      // rows base+q*1024+w*64+lane
    if ((t & 63) == 0) bw[q][t >> 6] = ba;
  }
  __syncthreads();
  if (b < NCH - 1 && t < CHUNK / 64) {            // wave 0: 64 words
    __hip_atomic_store(&bmg64[b * (CHUNK / 64) + t], bw[t >> 4][t & 15],
                       __ATOMIC_RELAXED, __HIP_MEMORY_SCOPE_AGENT);
  }
  if (t == 0)                                     // same wave: stores precede release
    __hip_atomic_store(progress, (unsigned int)(b + 1),
                       __ATOMIC_RELEASE, __HIP_MEMORY_SCOPE_AGENT);

  // ---- outputs (off the chain; block 36's knn overwrites dead bitmask) ----
#pragma unroll
  for (int q = 0; q < QRT; ++q)
    if (vq[q]) out[rowq[q]] = kq[q] ? 1 : 0;

#pragma unroll
  for (int q = 0; q < QRT; ++q) {
    if (!vq[q]) continue;
    const int row = rowq[q];
    const int* rp = knn + (long long)row * KNN;
    int* orow = out + M_ROWS + (long long)row * KNN;
    const bool k = kq[q];
#pragma unroll
    for (int u = 0; u < 16; ++u) {
      int4 d = ((const int4*)rp)[u];
      int4 o4;
      o4.x = k ? d.x : M_ROWS;
      o4.y = k ? d.y : M_ROWS;
      o4.z = k ? d.z : M_ROWS;
      o4.w = k ? d.w : M_ROWS;
      ((int4*)orow)[u] = o4;
    }
  }
}

extern "C" void kernel_launch(void* const* d_in, const int* in_sizes, int n_in,
                              void* d_out, int out_size, void* d_ws, size_t ws_size,
                              hipStream_t stream) {
  const int* knn = (const int*)d_in[1];
  int* out = (int*)d_out;
  unsigned int* progress = (unsigned int*)d_ws;

  init_ws_kernel<<<1, 64, 0, stream>>>(progress);
  nms_chain_kernel<<<NCH, BLK, 0, stream>>>(knn, out, progress);
}

// Round 9
// 630.127 us; speedup vs baseline: 11.6478x; 1.5102x over previous
//
#include <hip/hip_runtime.h>

// Greedy NMS: keep[i] = !any(keep[j] for j in knn[i] if j < i)
//
// Round-9: resident chained-chunk wavefront, 74 x 2048-row chunks.
// Round-8 finding: the pre-turn full-history row reload (512KB-1MB @ ~42 GB/s
// single-CU LLC bw) fired at progress==b-1 and WAS the step time -> chain
// total ~= M*256B / 42GB/s ~= 915us regardless of CHUNK. Fix:
//   - static 4-chunk window [base-4*CHUNK, base): pred lists (exl) recorded at
//     classification; on-turn resolution is LDS-only.
//   - exactly ONE reload pass per block, forced when progress >= b-4
//     (~4 steps of slack >> 12us reload) -> off the critical path.
//   - no GATE passes (reload cost is span-independent; they bought nothing).
//   - keep bits ballot-published into d_out's tail (last 73 rows' knn slots,
//     overwritten by block 73 after everyone's done reading); d_ws = 4B.
//   - one-barrier polls, wave-0 publish + release, in-kernel knn writes.
//
// Output encoding (validated round 4): INT32.
//   d_out[0..M)        : kept flags, 1 / 0
//   d_out[M..M+M*64)   : kept_knn, idx or 150000 (tail doubles as bitmask scratch)
// d_ws[0..3]: progress counter (zeroed by init kernel each call)

#define M_ROWS 150000
#define KNN    64
#define BLK    1024
#define QRT    2
#define CHUNK  (BLK * QRT)                        // 2048
#define NCH    ((M_ROWS + CHUNK - 1) / CHUNK)     // 74
#define ICAP   6
#define ECAP   12
#define WCH    4                                  // exl window, chunks
#define LMW    (((NCH - 1) * CHUNK) / 32)         // 4672 u32 bitmask words
#define OUT_INTS (M_ROWS + M_ROWS * KNN)
#define BMG_OFF  (OUT_INTS - LMW)

__global__ void init_ws_kernel(unsigned int* progress) {
  if (threadIdx.x == 0) *progress = 0u;
}

__device__ __forceinline__ unsigned int bm_load(const unsigned int* p) {
  return __hip_atomic_load(p, __ATOMIC_RELAXED, __HIP_MEMORY_SCOPE_AGENT);
}

// reload a row and probe preds j in [lo, hi) against the LDS bitmask
__device__ __forceinline__ bool probe_reload(const int* __restrict__ rp,
                                             const unsigned int* lm,
                                             int lo, int hi) {
  bool s = false;
#pragma unroll
  for (int u = 0; u < 16; ++u) {
    int4 d = ((const int4*)rp)[u];
    int js[4] = {d.x, d.y, d.z, d.w};
#pragma unroll
    for (int m = 0; m < 4; ++m) {
      int j = js[m];
      if (j >= lo && j < hi && ((lm[j >> 5] >> (j & 31)) & 1u)) s = true;
    }
  }
  return s;
}

__global__ __launch_bounds__(BLK) void nms_chain_kernel(
    const int* __restrict__ knn,
    int* __restrict__ out,
    unsigned int* __restrict__ progress)
{
  const int b    = blockIdx.x;
  const int t    = threadIdx.x;
  const int base = b * CHUNK;
  const int winb = (b > WCH) ? (base - WCH * CHUNK) : 0;   // exl window base

  unsigned int* bmg = (unsigned int*)out + BMG_OFF;
  unsigned long long* bmg64 = (unsigned long long*)bmg;

  __shared__ unsigned char      st[CHUNK];        // 0 unk, 1 kept, 2 supp
  __shared__ unsigned short     il[CHUNK][ICAP];  // intra-chunk pred offsets
  __shared__ unsigned short     exl[CHUNK][ECAP]; // window pred offsets
  __shared__ unsigned int       lm[LMW];          // mirrored keep bits
  __shared__ unsigned long long bw[QRT][BLK / 64];
  __shared__ unsigned int       prog_sh[2];

  int  rowq[QRT];
  bool vq[QRT], ovf[QRT], eovf[QRT], supp[QRT];
  int  ic[QRT], ec[QRT];

#pragma unroll
  for (int q = 0; q < QRT; ++q) {
    rowq[q] = base + q * BLK + t;
    vq[q]   = rowq[q] < M_ROWS;
    ic[q] = ec[q] = 0;
    ovf[q] = eovf[q] = supp[q] = false;
  }

  // ---- classification: intra-chunk + static-window pred lists ----
#pragma unroll
  for (int q = 0; q < QRT; ++q) {
    if (!vq[q]) continue;
    const int o   = q * BLK + t;
    const int row = rowq[q];
    const int* rp = knn + (long long)row * KNN;
#pragma unroll
    for (int u = 0; u < 16; ++u) {
      int4 d = ((const int4*)rp)[u];
      int js[4] = {d.x, d.y, d.z, d.w};
#pragma unroll
      for (int m = 0; m < 4; ++m) {
        int j = js[m];
        if (j < row) {                            // strict <: ref semantics
          if (j >= base) {
            if (ic[q] < ICAP) il[o][ic[q]] = (unsigned short)(j - base);
            ++ic[q];
          } else if (j >= winb) {
            if (ec[q] < ECAP) exl[o][ec[q]] = (unsigned short)(j - winb);
            ++ec[q];
          }
          // j < winb: covered by the single forced reload pass
        }
      }
    }
  }
#pragma unroll
  for (int q = 0; q < QRT; ++q) {
    ovf[q]  = ic[q] > ICAP; if (ovf[q])  ic[q] = ICAP;
    eovf[q] = ec[q] > ECAP; if (eovf[q]) ec[q] = ECAP;
  }

  // ---- wait loop: one barrier/iter; single forced reload pass at b-WCH ----
  bool reloaded = (b <= WCH);                     // small b: window covers all
  int  rel_lim  = 0;                              // bits probed in [0, rel_lim)
  int  wcop     = 0;
  for (int spin = 0; ; ++spin) {
    const int slot = spin & 1;
    if (t == 0)
      prog_sh[slot] = __hip_atomic_load(progress, __ATOMIC_RELAXED,
                                        __HIP_MEMORY_SCOPE_AGENT);
    __syncthreads();                              // slot reuse safe: 1 barrier apart
    const int praw = (int)prog_sh[slot];
    if (praw >= b) {                              // our turn
      const int wt = b * (CHUNK / 32);            // final lm catch-up
      for (int w = wcop + t; w < wt; w += BLK) lm[w] = bm_load(&bmg[w]);
      wcop = wt;
      __syncthreads();                            // lm visible
      break;
    }
    if (!reloaded && praw >= b - WCH) {           // forced pass: ~WCH steps slack
      const int wt = praw * (CHUNK / 32);
      for (int w = wcop + t; w < wt; w += BLK) lm[w] = bm_load(&bmg[w]);
      wcop = wt;
      __syncthreads();                            // lm visible
      const int lim = praw * CHUNK;
#pragma unroll
      for (int q = 0; q < QRT; ++q)
        if (vq[q] && !supp[q])
          supp[q] = probe_reload(knn + (long long)rowq[q] * KNN, lm, 0, lim);
      rel_lim  = lim;
      reloaded = true;
    }
    if (spin > (1 << 22)) break;                  // safety valve
    __builtin_amdgcn_s_sleep(1);
  }

  // ---- on-turn: rare catch-up + static-window LDS probes ----
  if (b > WCH && rel_lim < winb) {                // missed the forced tick (rare)
#pragma unroll
    for (int q = 0; q < QRT; ++q)
      if (vq[q] && !supp[q])
        supp[q] = probe_reload(knn + (long long)rowq[q] * KNN, lm, rel_lim, winb);
  }
  if (b > 0) {
#pragma unroll
    for (int q = 0; q < QRT; ++q) {
      if (!vq[q] || supp[q]) continue;
      if (!eovf[q]) {
        const int o = q * BLK + t;
        for (int x = 0; x < ec[q]; ++x) {
          int j = winb + (int)exl[o][x];
          if ((lm[j >> 5] >> (j & 31)) & 1u) { supp[q] = true; break; }
        }
      } else {                                    // >ECAP window preds (rare)
        supp[q] = probe_reload(knn + (long long)rowq[q] * KNN, lm, winb, base);
      }
    }
  }

  // ---- intra-chunk monotone fixed-point (validated rounds 4-8) ----
#pragma unroll
  for (int q = 0; q < QRT; ++q) {
    const int o = q * BLK + t;
    st[o] = (!vq[q] || supp[q]) ? (unsigned char)2
          : ((ic[q] == 0 && !ovf[q]) ? (unsigned char)1 : (unsigned char)0);
  }
  __syncthreads();

  for (int it = 0; it < CHUNK; ++it) {
    bool un = false;
#pragma unroll
    for (int q = 0; q < QRT; ++q) {
      const int o = q * BLK + t;
      if (st[o] == 0) {
        bool anyK = false, allD = true;
        if (!ovf[q]) {
          for (int x = 0; x < ic[q]; ++x) {
            unsigned char s = st[il[o][x]];
            anyK |= (s == 1); allD &= (s != 0);
          }
        } else {                                  // rare: rescan from global
          const int row = rowq[q];
          const int* rp = knn + (long long)row * KNN;
#pragma unroll
          for (int k = 0; k < KNN; ++k) {
            int j = rp[k];
            if (j >= base && j < row) {
              unsigned char s = st[j - base];
              anyK |= (s == 1); allD &= (s != 0);
            }
          }
        }
        if (anyK) st[o] = 2; else if (allD) st[o] = 1;
        if (st[o] == 0) un = true;
      }
    }
    if (__syncthreads_count((int)un) == 0) break;
  }

  // ---- publish: ballots -> LDS -> wave 0 stores + release ----
  bool kq[QRT];
#pragma unroll
  for (int q = 0; q < QRT; ++q)
    kq[q] = vq[q] && (st[q * BLK + t] == 1);

#pragma unroll
  for (int q = 0; q < QRT; ++q) {
    unsigned long long ba = __ballot(kq[q]);      // rows base+q*1024+w*64+lane
    if ((t & 63) == 0) bw[q][t >> 6] = ba;
  }
  __syncthreads();
  if (b < NCH - 1 && t < CHUNK / 64) {            // wave 0: 32 u64 words
    __hip_atomic_store(&bmg64[b * (CHUNK / 64) + t], bw[t >> 4][t & 15],
                       __ATOMIC_RELAXED, __HIP_MEMORY_SCOPE_AGENT);
  }
  if (t == 0)                                     // same wave: stores precede release
    __hip_atomic_store(progress, (unsigned int)(b + 1),
                       __ATOMIC_RELEASE, __HIP_MEMORY_SCOPE_AGENT);

  // ---- outputs (off the chain; block 73's knn overwrites dead bitmask) ----
#pragma unroll
  for (int q = 0; q < QRT; ++q)
    if (vq[q]) out[rowq[q]] = kq[q] ? 1 : 0;

#pragma unroll
  for (int q = 0; q < QRT; ++q) {
    if (!vq[q]) continue;
    const int row = rowq[q];
    const int* rp = knn + (long long)row * KNN;
    int* orow = out + M_ROWS + (long long)row * KNN;
    const bool k = kq[q];
#pragma unroll
    for (int u = 0; u < 16; ++u) {
      int4 d = ((const int4*)rp)[u];
      int4 o4;
      o4.x = k ? d.x : M_ROWS;
      o4.y = k ? d.y : M_ROWS;
      o4.z = k ? d.z : M_ROWS;
      o4.w = k ? d.w : M_ROWS;
      ((int4*)orow)[u] = o4;
    }
  }
}

extern "C" void kernel_launch(void* const* d_in, const int* in_sizes, int n_in,
                              void* d_out, int out_size, void* d_ws, size_t ws_size,
                              hipStream_t stream) {
  const int* knn = (const int*)d_in[1];
  int* out = (int*)d_out;
  unsigned int* progress = (unsigned int*)d_ws;

  init_ws_kernel<<<1, 64, 0, stream>>>(progress);
  nms_chain_kernel<<<NCH, BLK, 0, stream>>>(knn, out, progress);
}